// Round 1
// baseline (276.203 us; speedup 1.0000x reference)
//
#include <hip/hip_runtime.h>

// B=4, S=512, HID=1024, H=16, D=64, NREL=64
// ws: qb bf16(B,H,S,D) | kb bf16(B,H,S,D) | vt bf16(B,H,D,S) | attn_b bf16(B*S,HID)
//     Xq,Xk,Xv bf16 | Wqb,Wkb,Wvb,Wob bf16 | relkb bf16(64,64) | relvT bf16(64,64)

typedef __attribute__((ext_vector_type(8))) short bf16x8 __attribute__((may_alias));
typedef __attribute__((ext_vector_type(4))) float f32x4;

__device__ __forceinline__ short f2bf(float x) {
    unsigned u = __float_as_uint(x);
    u += 0x7fff + ((u >> 16) & 1);          // RNE; finite inputs
    return (short)(u >> 16);
}

__device__ __forceinline__ void async16(void* lds, const void* g) {
    __builtin_amdgcn_global_load_lds(
        (const __attribute__((address_space(1))) void*)g,
        (__attribute__((address_space(3))) void*)lds, 16, 0, 0);
}

// ---------- fused fp32 -> bf16 cast of 3 X (2M ea) + 4 W (1M ea) + rel tables ----------
__global__ __launch_bounds__(256)
void cast_all(const float* __restrict__ x0, const float* __restrict__ x1, const float* __restrict__ x2,
              const float* __restrict__ w0, const float* __restrict__ w1,
              const float* __restrict__ w2, const float* __restrict__ w3,
              const float* __restrict__ rk, const float* __restrict__ rv,
              short* __restrict__ y0, short* __restrict__ y1, short* __restrict__ y2,
              short* __restrict__ u0, short* __restrict__ u1,
              short* __restrict__ u2, short* __restrict__ u3,
              short* __restrict__ rkb, short* __restrict__ rvT)
{
    size_t i = (size_t)blockIdx.x * 256 + threadIdx.x;
    if (i < 2621440u) {
        const float* src; short* dst; size_t off;
        if (i < 3u*524288u) {
            int s = (int)(i / 524288u); off = i % 524288u;
            src = s == 0 ? x0 : (s == 1 ? x1 : x2);
            dst = s == 0 ? y0 : (s == 1 ? y1 : y2);
        } else {
            size_t j = i - 3u*524288u;
            int s = (int)(j / 262144u); off = j % 262144u;
            src = s == 0 ? w0 : (s == 1 ? w1 : (s == 2 ? w2 : w3));
            dst = s == 0 ? u0 : (s == 1 ? u1 : (s == 2 ? u2 : u3));
        }
        float4 f = ((const float4*)src)[off];
        short4 o; o.x = f2bf(f.x); o.y = f2bf(f.y); o.z = f2bf(f.z); o.w = f2bf(f.w);
        ((short4*)dst)[off] = o;
    } else if (i < 2621440u + 1024u) {
        size_t off = i - 2621440u;                 // relk: straight cast, 64x64
        float4 f = ((const float4*)rk)[off];
        short4 o; o.x = f2bf(f.x); o.y = f2bf(f.y); o.z = f2bf(f.z); o.w = f2bf(f.w);
        ((short4*)rkb)[off] = o;
    } else {
        int m = (int)(i - 2622464u);               // relv: transpose to [d][r], 64x64
        int d = m >> 4, r0 = (m & 15) * 4;
        short4 o;
        o.x = f2bf(rv[(size_t)(r0 + 0) * 64 + d]);
        o.y = f2bf(rv[(size_t)(r0 + 1) * 64 + d]);
        o.z = f2bf(rv[(size_t)(r0 + 2) * 64 + d]);
        o.w = f2bf(rv[(size_t)(r0 + 3) * 64 + d]);
        *(short4*)&rvT[d * 64 + r0] = o;
    }
}

// ---------- bf16 MFMA GEMM, tile 128(M)x64(N), BK=64, dbuf: O = A @ B^T + bias ----------
// 4 waves in 2x2; wave does 64(M)x32(N) = 4x2 MFMA tiles.
// mode 0: O fp32 flat (M,1024). mode 1: O bf16; z<2 -> (b,h,s,d); z==2 -> (b,h,d,s).
__global__ __launch_bounds__(256)
void gemm12864(const short* __restrict__ A0, const short* __restrict__ A1, const short* __restrict__ A2,
               const short* __restrict__ B0, const short* __restrict__ B1, const short* __restrict__ B2,
               const float* __restrict__ c0, const float* __restrict__ c1, const float* __restrict__ c2,
               void* __restrict__ O0, void* __restrict__ O1, void* __restrict__ O2,
               int mode)
{
    __shared__ short ldsw[2 * 12288];   // [buf][A 128*64 | B 64*64]; epilogue reuses as Tls

    const int z = blockIdx.z;
    const short* A    = z == 0 ? A0 : (z == 1 ? A1 : A2);
    const short* Bm   = z == 0 ? B0 : (z == 1 ? B1 : B2);
    const float* bias = z == 0 ? c0 : (z == 1 ? c1 : c2);
    void*        O    = z == 0 ? O0 : (z == 1 ? O1 : O2);

    const int t = threadIdx.x;
    const int lane = t & 63, w = t >> 6;
    const int wr = w >> 1, wc = w & 1;            // wave 2x2: wr -> 64-row half, wc -> 32-col half
    const int quad = lane >> 4, cl = lane & 15;
    const int rowBase = blockIdx.y * 128;
    const int colBase = blockIdx.x * 64;
    const int gl = ((lane & 7) - (lane >> 3)) & 7;

    f32x4 acc[4][2];
#pragma unroll
    for (int i = 0; i < 4; ++i)
#pragma unroll
        for (int j = 0; j < 2; ++j) acc[i][j] = (f32x4){0.f, 0.f, 0.f, 0.f};

    const int rstage = w * 8 + (lane >> 3);
    const short* Ag = A  + (size_t)(rowBase + rstage) * 1024 + gl * 8;
    const short* Bg = Bm + (size_t)(colBase + rstage) * 1024 + gl * 8;

    // prologue: stage tile 0 into buf 0
    {
        short* Als = ldsw;
        short* Bls = ldsw + 8192;
#pragma unroll
        for (int i = 0; i < 4; ++i)
            async16(&Als[(i * 32 + w * 8) * 64], Ag + (size_t)i * 32 * 1024);
#pragma unroll
        for (int i = 0; i < 2; ++i)
            async16(&Bls[(i * 32 + w * 8) * 64], Bg + (size_t)i * 32 * 1024);
    }

    for (int it = 0; it < 16; ++it) {
        const int cur = it & 1;
        __syncthreads();                          // drains vmcnt -> buf[cur] valid
        if (it < 15) {
            short* Als = ldsw + (cur ^ 1) * 12288;
            short* Bls = Als + 8192;
            const int k0 = (it + 1) * 64;
#pragma unroll
            for (int i = 0; i < 4; ++i)
                async16(&Als[(i * 32 + w * 8) * 64], Ag + (size_t)i * 32 * 1024 + k0);
#pragma unroll
            for (int i = 0; i < 2; ++i)
                async16(&Bls[(i * 32 + w * 8) * 64], Bg + (size_t)i * 32 * 1024 + k0);
        }
        const short* Als = ldsw + cur * 12288;
        const short* Bls = Als + 8192;
#pragma unroll
        for (int kk = 0; kk < 2; ++kk) {
            bf16x8 a[4], b[2];
#pragma unroll
            for (int mi = 0; mi < 4; ++mi) {
                int r = wr * 64 + mi * 16 + cl;
                int s = (kk * 4 + quad + r) & 7;
                a[mi] = *(const bf16x8*)&Als[r * 64 + s * 8];
            }
#pragma unroll
            for (int ni = 0; ni < 2; ++ni) {
                int r = wc * 32 + ni * 16 + cl;
                int s = (kk * 4 + quad + r) & 7;
                b[ni] = *(const bf16x8*)&Bls[r * 64 + s * 8];
            }
#pragma unroll
            for (int mi = 0; mi < 4; ++mi)
#pragma unroll
                for (int ni = 0; ni < 2; ++ni)
                    acc[mi][ni] = __builtin_amdgcn_mfma_f32_16x16x32_bf16(
                        a[mi], b[ni], acc[mi][ni], 0, 0, 0);
        }
    }

    if (mode == 0) {
        // flat f32 (M,1024)
#pragma unroll
        for (int mi = 0; mi < 4; ++mi)
#pragma unroll
            for (int ni = 0; ni < 2; ++ni) {
                int col = colBase + wc * 32 + ni * 16 + cl;
                float bv = bias[col];
#pragma unroll
                for (int reg = 0; reg < 4; ++reg) {
                    int row = rowBase + wr * 64 + mi * 16 + quad * 4 + reg;
                    ((float*)O)[(size_t)row * 1024 + col] = acc[mi][ni][reg] + bv;
                }
            }
        return;
    }

    __syncthreads();                              // staging reads done before Tls reuse
    short* Tls = ldsw;
    if (z == 2) {
        // vt (b,h,d,s): Tls[64][136]
#pragma unroll
        for (int mi = 0; mi < 4; ++mi)
#pragma unroll
            for (int ni = 0; ni < 2; ++ni) {
                int d = wc * 32 + ni * 16 + cl;
                float bv = bias[colBase + d];
                short4 pk;
                pk.x = f2bf(acc[mi][ni][0] + bv);
                pk.y = f2bf(acc[mi][ni][1] + bv);
                pk.z = f2bf(acc[mi][ni][2] + bv);
                pk.w = f2bf(acc[mi][ni][3] + bv);
                int sl = wr * 64 + mi * 16 + quad * 4;
                *(short4*)&Tls[d * 136 + sl] = pk;
            }
        __syncthreads();
        int d = t >> 2, s0 = (t & 3) * 32;
        int bb = rowBase >> 9, sBase = rowBase & 511, hh = colBase >> 6;
        short* dst = (short*)O + (((size_t)(bb * 16 + hh) * 64 + d) << 9) + sBase + s0;
#pragma unroll
        for (int j = 0; j < 4; ++j)
            *(bf16x8*)(dst + j * 8) = *(const bf16x8*)&Tls[d * 136 + s0 + j * 8];
    } else {
        // bhsd: Tls[128][72] (one head: colBase is 64-aligned, N=64)
#pragma unroll
        for (int mi = 0; mi < 4; ++mi)
#pragma unroll
            for (int ni = 0; ni < 2; ++ni) {
                int d = wc * 32 + ni * 16 + cl;
                float bv = bias[colBase + d];
#pragma unroll
                for (int reg = 0; reg < 4; ++reg) {
                    int sl = wr * 64 + mi * 16 + quad * 4 + reg;
                    Tls[sl * 72 + d] = f2bf(acc[mi][ni][reg] + bv);
                }
            }
        __syncthreads();
        int sl = t >> 1, half = t & 1;
        int bb = rowBase >> 9, sBase = rowBase & 511, hh = colBase >> 6;
        short* dst = (short*)O + (((size_t)(bb * 16 + hh) * 512 + sBase + sl) << 6) + half * 32;
#pragma unroll
        for (int j = 0; j < 4; ++j)
            *(bf16x8*)(dst + j * 8) = *(const bf16x8*)&Tls[sl * 72 + half * 32 + j * 8];
    }
}

// ---------------- Attention: 4-wave workgroups, K split across waves ----------------
// block = 256 threads = 4 waves, one (b,h, 16-query tile) x all 512 keys.
// Wave w handles keys [128w, 128w+128) (2 chunks of 64). No-max softmax makes all
// partials additive: bins/lsum accumulate via LDS atomics, O via obuf (reuses Pst).
// LDS: qwr f32[16][68] | bins f32[16][68] | lsum f32[16] | Pst short[4][16][72]
//      post-K: obuf f32[16][68] and binsBf short[16][72] alias the Pst region.
// Grid swizzle: bh = bid & 63 so same-bh blocks share an XCD (bid%8 = bh%8).
#define AT_QWR  0
#define AT_BINS 4352
#define AT_LSUM 8704
#define AT_PST  8768
#define AT_TOT  (8768 + 4 * 2304)     // 17984 B

__global__ __launch_bounds__(256, 4)   // min 4 waves/EU -> VGPR<=128 -> 16 waves/CU
void attn_kernel(const short* __restrict__ qg, const short* __restrict__ kg,
                 const short* __restrict__ vtg, const int* __restrict__ mask,
                 const short* __restrict__ relkb, const short* __restrict__ relvT,
                 short* __restrict__ attn_b)
{
    __shared__ __align__(16) char pool[AT_TOT];
    float* qwr  = (float*)(pool + AT_QWR);
    float* bins = (float*)(pool + AT_BINS);
    float* lsum = (float*)(pool + AT_LSUM);
    short* Pst  = (short*)(pool + AT_PST);

    const int t = threadIdx.x;
    const int lane = t & 63, w = t >> 6;
    const int quad = lane >> 4, cl = lane & 15;
    const int bid = blockIdx.x;
    const int bh = bid & 63, qbk = bid >> 6;   // XCD-friendly: bh%8 fixes XCD
    const int b = bh >> 4, h = bh & 15, q0 = qbk * 16;

    const short* qbase = qg  + ((size_t)bh * 512 + q0) * 64;
    const short* kbase = kg  + (size_t)bh * 512 * 64;
    const short* vbase = vtg + (size_t)bh * 64 * 512;
    const int*   mb    = mask + (size_t)b * 512 * 512 + (size_t)q0 * 512;

    // zero bins + lsum
    for (int i = t; i < 16 * 68; i += 256) bins[i] = 0.f;
    if (t < 16) lsum[t] = 0.f;

    // Q A-fragments direct from global (same for all 4 waves; L1-served)
    bf16x8 qa0 = *(const bf16x8*)(qbase + cl * 64 + quad * 8);
    bf16x8 qa1 = *(const bf16x8*)(qbase + cl * 64 + 32 + quad * 8);

    // qrel: wave w computes r-tile rt = w
    {
        const short* kp = relkb + (size_t)(w * 16 + cl) * 64 + quad * 8;
        bf16x8 rb0 = *(const bf16x8*)kp;
        bf16x8 rb1 = *(const bf16x8*)(kp + 32);
        f32x4 qr = (f32x4){0.f, 0.f, 0.f, 0.f};
        qr = __builtin_amdgcn_mfma_f32_16x16x32_bf16(qa0, rb0, qr, 0, 0, 0);
        qr = __builtin_amdgcn_mfma_f32_16x16x32_bf16(qa1, rb1, qr, 0, 0, 0);
#pragma unroll
        for (int reg = 0; reg < 4; ++reg)
            qwr[(quad * 4 + reg) * 68 + w * 16 + cl] = qr[reg];
    }
    __syncthreads();                    // qwr + bins + lsum ready

    // ---- K-loop: wave w -> chunks 2w, 2w+1 (128 keys) ----
    f32x4 oacc[4];
#pragma unroll
    for (int dt = 0; dt < 4; ++dt) oacc[dt] = (f32x4){0.f, 0.f, 0.f, 0.f};
    float lpart[4] = {0.f, 0.f, 0.f, 0.f};
    short* myPst = Pst + w * 1152;      // 16*72 shorts, wave-private

#pragma unroll
    for (int cc = 0; cc < 2; ++cc) {
        const int k0 = (w * 2 + cc) * 64;
        // prefetch all 16 mask ids for this chunk (independent loads, issue early)
        int ids[4][4];
#pragma unroll
        for (int nt = 0; nt < 4; ++nt)
#pragma unroll
            for (int reg = 0; reg < 4; ++reg)
                ids[nt][reg] = mb[(size_t)(quad * 4 + reg) * 512 + k0 + nt * 16 + cl];

#pragma unroll
        for (int nt = 0; nt < 4; ++nt) {
            const int kidx = k0 + nt * 16 + cl;
            const short* kp = kbase + (size_t)kidx * 64 + quad * 8;
            bf16x8 kb0 = *(const bf16x8*)kp;
            bf16x8 kb1 = *(const bf16x8*)(kp + 32);
            f32x4 s = (f32x4){0.f, 0.f, 0.f, 0.f};
            s = __builtin_amdgcn_mfma_f32_16x16x32_bf16(qa0, kb0, s, 0, 0, 0);
            s = __builtin_amdgcn_mfma_f32_16x16x32_bf16(qa1, kb1, s, 0, 0, 0);
#pragma unroll
            for (int reg = 0; reg < 4; ++reg) {
                int q = quad * 4 + reg;
                int id = ids[nt][reg];
                float sc = (s[reg] + 0.25f * qwr[q * 68 + id]) * 0.125f;
                float p = (id == 0) ? 0.f : __expf(sc);   // no-max softmax; masked -> 0
                lpart[reg] += p;
                atomicAdd(&bins[q * 68 + id], p);
                myPst[q * 72 + nt * 16 + cl] = f2bf(p);
            }
        }
        // P C-layout -> A-layout via wave-private LDS (in-wave RAW via lgkmcnt)
        bf16x8 pa0 = *(const bf16x8*)&myPst[cl * 72 + quad * 8];
        bf16x8 pa1 = *(const bf16x8*)&myPst[cl * 72 + 32 + quad * 8];
#pragma unroll
        for (int dt = 0; dt < 4; ++dt) {
            const short* vp = vbase + (size_t)(dt * 16 + cl) * 512 + k0 + quad * 8;
            bf16x8 vb0 = *(const bf16x8*)vp;
            bf16x8 vb1 = *(const bf16x8*)(vp + 32);
            oacc[dt] = __builtin_amdgcn_mfma_f32_16x16x32_bf16(pa0, vb0, oacc[dt], 0, 0, 0);
            oacc[dt] = __builtin_amdgcn_mfma_f32_16x16x32_bf16(pa1, vb1, oacc[dt], 0, 0, 0);
        }
    }

    // per-q partial softmax denominators -> lsum (16-lane groups share q)
#pragma unroll
    for (int reg = 0; reg < 4; ++reg) {
        float l = lpart[reg];
#pragma unroll
        for (int m = 8; m >= 1; m >>= 1) l += __shfl_xor(l, m);
        lpart[reg] = l;
    }
    if ((lane & 15) == 0) {
#pragma unroll
        for (int reg = 0; reg < 4; ++reg)
            atomicAdd(&lsum[quad * 4 + reg], lpart[reg]);
    }
    __syncthreads();                    // bins + lsum complete; all Pst dead

    // combine O partials across waves via obuf (aliases Pst region)
    float* obuf   = (float*)(pool + AT_PST);            // 16*68 f32 = 4352 B
    short* binsBf = (short*)(pool + AT_PST + 4352);     // 16*72 bf16 = 2304 B
    for (int i = t; i < 16 * 68; i += 256) obuf[i] = 0.f;
    __syncthreads();
#pragma unroll
    for (int dt = 0; dt < 4; ++dt)
#pragma unroll
        for (int reg = 0; reg < 4; ++reg)
            atomicAdd(&obuf[(quad * 4 + reg) * 68 + dt * 16 + cl], oacc[dt][reg]);
    __syncthreads();

    // bins -> bf16 (256 threads, 4 elems each)
    {
        int row = t >> 4, c0 = (t & 15) * 4;
        float4 f = *(const float4*)&bins[row * 68 + c0];
        short4 o;
        o.x = f2bf(f.x); o.y = f2bf(f.y); o.z = f2bf(f.z); o.w = f2bf(f.w);
        *(short4*)&binsBf[row * 72 + c0] = o;
    }
    __syncthreads();

    // rel_out = bins @ relv for d-tile dt = w; combine + normalize + store
    bf16x8 ba0 = *(const bf16x8*)&binsBf[cl * 72 + quad * 8];
    bf16x8 ba1 = *(const bf16x8*)&binsBf[cl * 72 + 32 + quad * 8];
    const short* rp = relvT + (size_t)(w * 16 + cl) * 64 + quad * 8;
    bf16x8 rv0 = *(const bf16x8*)rp;
    bf16x8 rv1 = *(const bf16x8*)(rp + 32);
    f32x4 racc = (f32x4){0.f, 0.f, 0.f, 0.f};
    racc = __builtin_amdgcn_mfma_f32_16x16x32_bf16(ba0, rv0, racc, 0, 0, 0);
    racc = __builtin_amdgcn_mfma_f32_16x16x32_bf16(ba1, rv1, racc, 0, 0, 0);
#pragma unroll
    for (int reg = 0; reg < 4; ++reg) {
        int q = quad * 4 + reg;
        float val = (obuf[q * 68 + w * 16 + cl] + 0.25f * racc[reg]) / lsum[q];
        attn_b[(size_t)(b * 512 + q0 + q) * 1024 + h * 64 + w * 16 + cl] = f2bf(val);
    }
}

extern "C" void kernel_launch(void* const* d_in, const int* in_sizes, int n_in,
                              void* d_out, int out_size, void* d_ws, size_t ws_size,
                              hipStream_t stream)
{
    const float* q_in = (const float*)d_in[0];
    const float* k_in = (const float*)d_in[1];
    const float* v_in = (const float*)d_in[2];
    const int*   mask = (const int*)d_in[3];
    const float* Wq   = (const float*)d_in[4];
    const float* bq   = (const float*)d_in[5];
    const float* Wk   = (const float*)d_in[6];
    const float* bk   = (const float*)d_in[7];
    const float* Wv   = (const float*)d_in[8];
    const float* bv   = (const float*)d_in[9];
    const float* Wo   = (const float*)d_in[10];
    const float* bo   = (const float*)d_in[11];
    const float* relk = (const float*)d_in[12];
    const float* relv = (const float*)d_in[13];

    char* ws = (char*)d_ws;
    short* qb     = (short*)(ws);                  // 4MB
    short* kb     = (short*)(ws + (4u  << 20));    // 4MB
    short* vt     = (short*)(ws + (8u  << 20));    // 4MB
    short* attn_b = (short*)(ws + (12u << 20));    // 4MB
    short* Xq     = (short*)(ws + (16u << 20));    // 4MB
    short* Xk     = (short*)(ws + (20u << 20));
    short* Xv     = (short*)(ws + (24u << 20));
    short* Wqb    = (short*)(ws + (28u << 20));    // 2MB
    short* Wkb    = (short*)(ws + (30u << 20));
    short* Wvb    = (short*)(ws + (32u << 20));
    short* Wob    = (short*)(ws + (34u << 20));
    short* relkb  = (short*)(ws + (36u << 20));            // 8KB
    short* relvT  = (short*)(ws + (36u << 20) + 8192);     // 8KB

    cast_all<<<10248, 256, 0, stream>>>(q_in, k_in, v_in, Wq, Wk, Wv, Wo, relk, relv,
                                        Xq, Xk, Xv, Wqb, Wkb, Wvb, Wob, relkb, relvT);

    gemm12864<<<dim3(16, 16, 3), 256, 0, stream>>>(
        Xq, Xk, Xv, Wqb, Wkb, Wvb, bq, bk, bv, qb, kb, vt, 1);

    attn_kernel<<<dim3(2048), 256, 0, stream>>>(qb, kb, vt, mask, relkb, relvT, attn_b);

    gemm12864<<<dim3(16, 16, 1), 256, 0, stream>>>(
        attn_b, attn_b, attn_b, Wob, Wob, Wob, bo, bo, bo,
        (void*)d_out, (void*)d_out, (void*)d_out, 0);
}

// Round 2
// 245.880 us; speedup vs baseline: 1.1233x; 1.1233x over previous
//
#include <hip/hip_runtime.h>

// B=4, S=512, HID=1024, H=16, D=64, NREL=64
// ws: qb bf16(B,H,S,D) | kb bf16(B,H,S,D) | vt bf16(B,H,D,S) | attn_b bf16(B*S,HID)
//     Xq,Xk,Xv bf16 | Wqb,Wkb,Wvb,Wob bf16 | relkb bf16(64,64) | relvT bf16(64,64)

typedef __attribute__((ext_vector_type(8))) short bf16x8 __attribute__((may_alias));
typedef __attribute__((ext_vector_type(4))) float f32x4;

__device__ __forceinline__ short f2bf(float x) {
    unsigned u = __float_as_uint(x);
    u += 0x7fff + ((u >> 16) & 1);          // RNE; finite inputs
    return (short)(u >> 16);
}

__device__ __forceinline__ void async16(void* lds, const void* g) {
    __builtin_amdgcn_global_load_lds(
        (const __attribute__((address_space(1))) void*)g,
        (__attribute__((address_space(3))) void*)lds, 16, 0, 0);
}

// ---------- fused fp32 -> bf16 cast of 3 X (2M ea) + 4 W (1M ea) + rel tables ----------
__global__ __launch_bounds__(256)
void cast_all(const float* __restrict__ x0, const float* __restrict__ x1, const float* __restrict__ x2,
              const float* __restrict__ w0, const float* __restrict__ w1,
              const float* __restrict__ w2, const float* __restrict__ w3,
              const float* __restrict__ rk, const float* __restrict__ rv,
              short* __restrict__ y0, short* __restrict__ y1, short* __restrict__ y2,
              short* __restrict__ u0, short* __restrict__ u1,
              short* __restrict__ u2, short* __restrict__ u3,
              short* __restrict__ rkb, short* __restrict__ rvT)
{
    size_t i = (size_t)blockIdx.x * 256 + threadIdx.x;
    if (i < 2621440u) {
        const float* src; short* dst; size_t off;
        if (i < 3u*524288u) {
            int s = (int)(i / 524288u); off = i % 524288u;
            src = s == 0 ? x0 : (s == 1 ? x1 : x2);
            dst = s == 0 ? y0 : (s == 1 ? y1 : y2);
        } else {
            size_t j = i - 3u*524288u;
            int s = (int)(j / 262144u); off = j % 262144u;
            src = s == 0 ? w0 : (s == 1 ? w1 : (s == 2 ? w2 : w3));
            dst = s == 0 ? u0 : (s == 1 ? u1 : (s == 2 ? u2 : u3));
        }
        float4 f = ((const float4*)src)[off];
        short4 o; o.x = f2bf(f.x); o.y = f2bf(f.y); o.z = f2bf(f.z); o.w = f2bf(f.w);
        ((short4*)dst)[off] = o;
    } else if (i < 2621440u + 1024u) {
        size_t off = i - 2621440u;                 // relk: straight cast, 64x64
        float4 f = ((const float4*)rk)[off];
        short4 o; o.x = f2bf(f.x); o.y = f2bf(f.y); o.z = f2bf(f.z); o.w = f2bf(f.w);
        ((short4*)rkb)[off] = o;
    } else {
        int m = (int)(i - 2622464u);               // relv: transpose to [d][r], 64x64
        int d = m >> 4, r0 = (m & 15) * 4;
        short4 o;
        o.x = f2bf(rv[(size_t)(r0 + 0) * 64 + d]);
        o.y = f2bf(rv[(size_t)(r0 + 1) * 64 + d]);
        o.z = f2bf(rv[(size_t)(r0 + 2) * 64 + d]);
        o.w = f2bf(rv[(size_t)(r0 + 3) * 64 + d]);
        *(short4*)&rvT[d * 64 + r0] = o;
    }
}

// ---------- bf16 MFMA GEMM, tile 128(M)x64(N), BK=64, dbuf: O = A @ B^T + bias ----------
// 4 waves in 2x2; wave does 64(M)x32(N) = 4x2 MFMA tiles.
// mode 0: O fp32 flat (M,1024). mode 1: O bf16; z<2 -> (b,h,s,d); z==2 -> (b,h,d,s).
__global__ __launch_bounds__(256)
void gemm12864(const short* __restrict__ A0, const short* __restrict__ A1, const short* __restrict__ A2,
               const short* __restrict__ B0, const short* __restrict__ B1, const short* __restrict__ B2,
               const float* __restrict__ c0, const float* __restrict__ c1, const float* __restrict__ c2,
               void* __restrict__ O0, void* __restrict__ O1, void* __restrict__ O2,
               int mode)
{
    __shared__ short ldsw[2 * 12288];   // [buf][A 128*64 | B 64*64]; epilogue reuses as Tls

    const int z = blockIdx.z;
    const short* A    = z == 0 ? A0 : (z == 1 ? A1 : A2);
    const short* Bm   = z == 0 ? B0 : (z == 1 ? B1 : B2);
    const float* bias = z == 0 ? c0 : (z == 1 ? c1 : c2);
    void*        O    = z == 0 ? O0 : (z == 1 ? O1 : O2);

    const int t = threadIdx.x;
    const int lane = t & 63, w = t >> 6;
    const int wr = w >> 1, wc = w & 1;            // wave 2x2: wr -> 64-row half, wc -> 32-col half
    const int quad = lane >> 4, cl = lane & 15;
    const int rowBase = blockIdx.y * 128;
    const int colBase = blockIdx.x * 64;
    const int gl = ((lane & 7) - (lane >> 3)) & 7;

    f32x4 acc[4][2];
#pragma unroll
    for (int i = 0; i < 4; ++i)
#pragma unroll
        for (int j = 0; j < 2; ++j) acc[i][j] = (f32x4){0.f, 0.f, 0.f, 0.f};

    const int rstage = w * 8 + (lane >> 3);
    const short* Ag = A  + (size_t)(rowBase + rstage) * 1024 + gl * 8;
    const short* Bg = Bm + (size_t)(colBase + rstage) * 1024 + gl * 8;

    // prologue: stage tile 0 into buf 0
    {
        short* Als = ldsw;
        short* Bls = ldsw + 8192;
#pragma unroll
        for (int i = 0; i < 4; ++i)
            async16(&Als[(i * 32 + w * 8) * 64], Ag + (size_t)i * 32 * 1024);
#pragma unroll
        for (int i = 0; i < 2; ++i)
            async16(&Bls[(i * 32 + w * 8) * 64], Bg + (size_t)i * 32 * 1024);
    }

    for (int it = 0; it < 16; ++it) {
        const int cur = it & 1;
        __syncthreads();                          // drains vmcnt -> buf[cur] valid
        if (it < 15) {
            short* Als = ldsw + (cur ^ 1) * 12288;
            short* Bls = Als + 8192;
            const int k0 = (it + 1) * 64;
#pragma unroll
            for (int i = 0; i < 4; ++i)
                async16(&Als[(i * 32 + w * 8) * 64], Ag + (size_t)i * 32 * 1024 + k0);
#pragma unroll
            for (int i = 0; i < 2; ++i)
                async16(&Bls[(i * 32 + w * 8) * 64], Bg + (size_t)i * 32 * 1024 + k0);
        }
        const short* Als = ldsw + cur * 12288;
        const short* Bls = Als + 8192;
#pragma unroll
        for (int kk = 0; kk < 2; ++kk) {
            bf16x8 a[4], b[2];
#pragma unroll
            for (int mi = 0; mi < 4; ++mi) {
                int r = wr * 64 + mi * 16 + cl;
                int s = (kk * 4 + quad + r) & 7;
                a[mi] = *(const bf16x8*)&Als[r * 64 + s * 8];
            }
#pragma unroll
            for (int ni = 0; ni < 2; ++ni) {
                int r = wc * 32 + ni * 16 + cl;
                int s = (kk * 4 + quad + r) & 7;
                b[ni] = *(const bf16x8*)&Bls[r * 64 + s * 8];
            }
#pragma unroll
            for (int mi = 0; mi < 4; ++mi)
#pragma unroll
                for (int ni = 0; ni < 2; ++ni)
                    acc[mi][ni] = __builtin_amdgcn_mfma_f32_16x16x32_bf16(
                        a[mi], b[ni], acc[mi][ni], 0, 0, 0);
        }
    }

    if (mode == 0) {
        // flat f32 (M,1024)
#pragma unroll
        for (int mi = 0; mi < 4; ++mi)
#pragma unroll
            for (int ni = 0; ni < 2; ++ni) {
                int col = colBase + wc * 32 + ni * 16 + cl;
                float bv = bias[col];
#pragma unroll
                for (int reg = 0; reg < 4; ++reg) {
                    int row = rowBase + wr * 64 + mi * 16 + quad * 4 + reg;
                    ((float*)O)[(size_t)row * 1024 + col] = acc[mi][ni][reg] + bv;
                }
            }
        return;
    }

    __syncthreads();                              // staging reads done before Tls reuse
    short* Tls = ldsw;
    if (z == 2) {
        // vt (b,h,d,s): Tls[64][136]
#pragma unroll
        for (int mi = 0; mi < 4; ++mi)
#pragma unroll
            for (int ni = 0; ni < 2; ++ni) {
                int d = wc * 32 + ni * 16 + cl;
                float bv = bias[colBase + d];
                short4 pk;
                pk.x = f2bf(acc[mi][ni][0] + bv);
                pk.y = f2bf(acc[mi][ni][1] + bv);
                pk.z = f2bf(acc[mi][ni][2] + bv);
                pk.w = f2bf(acc[mi][ni][3] + bv);
                int sl = wr * 64 + mi * 16 + quad * 4;
                *(short4*)&Tls[d * 136 + sl] = pk;
            }
        __syncthreads();
        int d = t >> 2, s0 = (t & 3) * 32;
        int bb = rowBase >> 9, sBase = rowBase & 511, hh = colBase >> 6;
        short* dst = (short*)O + (((size_t)(bb * 16 + hh) * 64 + d) << 9) + sBase + s0;
#pragma unroll
        for (int j = 0; j < 4; ++j)
            *(bf16x8*)(dst + j * 8) = *(const bf16x8*)&Tls[d * 136 + s0 + j * 8];
    } else {
        // bhsd: Tls[128][72] (one head: colBase is 64-aligned, N=64)
#pragma unroll
        for (int mi = 0; mi < 4; ++mi)
#pragma unroll
            for (int ni = 0; ni < 2; ++ni) {
                int d = wc * 32 + ni * 16 + cl;
                float bv = bias[colBase + d];
#pragma unroll
                for (int reg = 0; reg < 4; ++reg) {
                    int sl = wr * 64 + mi * 16 + quad * 4 + reg;
                    Tls[sl * 72 + d] = f2bf(acc[mi][ni][reg] + bv);
                }
            }
        __syncthreads();
        int sl = t >> 1, half = t & 1;
        int bb = rowBase >> 9, sBase = rowBase & 511, hh = colBase >> 6;
        short* dst = (short*)O + (((size_t)(bb * 16 + hh) * 512 + sBase + sl) << 6) + half * 32;
#pragma unroll
        for (int j = 0; j < 4; ++j)
            *(bf16x8*)(dst + j * 8) = *(const bf16x8*)&Tls[sl * 72 + half * 32 + j * 8];
    }
}

// ---------------- Attention: 1-wave blocks, software-pipelined K-loop ----------------
// block = one 64-thread wave = (b,h, 16-query tile) x all 512 keys, zero barriers.
// Fully-unrolled 8-chunk loop; K-fragments and mask-ids double-buffered in registers
// (prefetch chunk c+1 at top of chunk c); V[c] and the qwr gathers issued at chunk top
// so their latency hides under the QK MFMAs. All LDS wave-private (lgkmcnt ordering).
// Grid swizzle: bh = bid & 63 so same-bh blocks share an XCD (bid%8 = bh%8).
#define AT_BINS 4352
#define AT_PST  8704
#define AT_TOT  11264

__global__ __launch_bounds__(64, 2)   // VGPR <= 256 -> grid's 8 blocks/CU stay resident
void attn_kernel(const short* __restrict__ qg, const short* __restrict__ kg,
                 const short* __restrict__ vtg, const int* __restrict__ mask,
                 const short* __restrict__ relkb, const short* __restrict__ relvT,
                 short* __restrict__ attn_b)
{
    __shared__ __align__(16) char pool[AT_TOT];
    float* qwr    = (float*)pool;
    float* bins   = (float*)(pool + AT_BINS);
    short* Pst    = (short*)(pool + AT_PST);
    short* binsBf = Pst;                       // aliases Pst after K-loop (Pst dead)

    const int lane = threadIdx.x;
    const int quad = lane >> 4, cl = lane & 15;
    const int bid = blockIdx.x;
    const int bh = bid & 63, qbk = bid >> 6;   // XCD-friendly: bh%8 fixes XCD
    const int b = bh >> 4, h = bh & 15, q0 = qbk * 16;

    const short* qbase = qg  + ((size_t)bh * 512 + q0) * 64;
    const short* kbase = kg  + (size_t)bh * 512 * 64;
    const short* vbase = vtg + (size_t)bh * 64 * 512;
    const int*   mb    = mask + (size_t)b * 512 * 512 + (size_t)q0 * 512;

    // zero bins
    for (int i = lane; i < 16 * 68; i += 64) bins[i] = 0.f;

    // Q A-fragments direct from global
    bf16x8 qa0 = *(const bf16x8*)(qbase + cl * 64 + quad * 8);
    bf16x8 qa1 = *(const bf16x8*)(qbase + cl * 64 + 32 + quad * 8);

    // prefetch chunk 0: K fragments + mask ids (fly during qrel compute)
    bf16x8 kbuf[2][8];
    int    idb[2][16];
#pragma unroll
    for (int nt = 0; nt < 4; ++nt) {
        const short* kp = kbase + (size_t)(nt * 16 + cl) * 64 + quad * 8;
        kbuf[0][nt * 2]     = *(const bf16x8*)kp;
        kbuf[0][nt * 2 + 1] = *(const bf16x8*)(kp + 32);
    }
#pragma unroll
    for (int nt = 0; nt < 4; ++nt)
#pragma unroll
        for (int reg = 0; reg < 4; ++reg)
            idb[0][nt * 4 + reg] = mb[(size_t)(quad * 4 + reg) * 512 + nt * 16 + cl];

    // qrel: all 4 r-tiles (bf16 table, vector loads)
#pragma unroll
    for (int rt = 0; rt < 4; ++rt) {
        const short* kp = relkb + (size_t)(rt * 16 + cl) * 64 + quad * 8;
        bf16x8 rb0 = *(const bf16x8*)kp;
        bf16x8 rb1 = *(const bf16x8*)(kp + 32);
        f32x4 qr = (f32x4){0.f, 0.f, 0.f, 0.f};
        qr = __builtin_amdgcn_mfma_f32_16x16x32_bf16(qa0, rb0, qr, 0, 0, 0);
        qr = __builtin_amdgcn_mfma_f32_16x16x32_bf16(qa1, rb1, qr, 0, 0, 0);
#pragma unroll
        for (int reg = 0; reg < 4; ++reg)
            qwr[(quad * 4 + reg) * 68 + rt * 16 + cl] = qr[reg];
    }

    // ---- K-loop: 8 chunks of 64 keys, fully unrolled + register double-buffered ----
    f32x4 oacc[4];
#pragma unroll
    for (int dt = 0; dt < 4; ++dt) oacc[dt] = (f32x4){0.f, 0.f, 0.f, 0.f};
    float lpart[4] = {0.f, 0.f, 0.f, 0.f};

#pragma unroll
    for (int c = 0; c < 8; ++c) {
        const int cur = c & 1, nxt = cur ^ 1;
        const int k0 = c * 64;

        // qwr gathers for this chunk (only need ids; hide LDS latency under MFMAs)
        float qv[16];
#pragma unroll
        for (int e = 0; e < 16; ++e)
            qv[e] = qwr[(quad * 4 + (e & 3)) * 68 + idb[cur][e]];

        // V prefetch for this chunk (used after softmax)
        bf16x8 vb[8];
#pragma unroll
        for (int dt = 0; dt < 4; ++dt) {
            const short* vp = vbase + (size_t)(dt * 16 + cl) * 512 + k0 + quad * 8;
            vb[dt * 2]     = *(const bf16x8*)vp;
            vb[dt * 2 + 1] = *(const bf16x8*)(vp + 32);
        }

        // next-chunk K + ids prefetch (used one full chunk later)
        if (c < 7) {
            const int k1 = k0 + 64;
#pragma unroll
            for (int nt = 0; nt < 4; ++nt) {
                const short* kp = kbase + (size_t)(k1 + nt * 16 + cl) * 64 + quad * 8;
                kbuf[nxt][nt * 2]     = *(const bf16x8*)kp;
                kbuf[nxt][nt * 2 + 1] = *(const bf16x8*)(kp + 32);
            }
#pragma unroll
            for (int nt = 0; nt < 4; ++nt)
#pragma unroll
                for (int reg = 0; reg < 4; ++reg)
                    idb[nxt][nt * 4 + reg] = mb[(size_t)(quad * 4 + reg) * 512 + k1 + nt * 16 + cl];
        }

        // QK^T + softmax numerator -> Pst
#pragma unroll
        for (int nt = 0; nt < 4; ++nt) {
            f32x4 s = (f32x4){0.f, 0.f, 0.f, 0.f};
            s = __builtin_amdgcn_mfma_f32_16x16x32_bf16(qa0, kbuf[cur][nt * 2],     s, 0, 0, 0);
            s = __builtin_amdgcn_mfma_f32_16x16x32_bf16(qa1, kbuf[cur][nt * 2 + 1], s, 0, 0, 0);
#pragma unroll
            for (int reg = 0; reg < 4; ++reg) {
                int q = quad * 4 + reg;
                int id = idb[cur][nt * 4 + reg];
                float sc = fmaf(qv[nt * 4 + reg], 0.03125f, s[reg] * 0.125f);
                float p = (id == 0) ? 0.f : __expf(sc);   // no-max softmax; masked -> 0
                lpart[reg] += p;
                atomicAdd(&bins[q * 68 + id], p);
                Pst[q * 72 + nt * 16 + cl] = f2bf(p);
            }
        }
        // P C-layout -> A-layout via wave-private LDS (in-wave RAW via lgkmcnt)
        bf16x8 pa0 = *(const bf16x8*)&Pst[cl * 72 + quad * 8];
        bf16x8 pa1 = *(const bf16x8*)&Pst[cl * 72 + 32 + quad * 8];
#pragma unroll
        for (int dt = 0; dt < 4; ++dt) {
            oacc[dt] = __builtin_amdgcn_mfma_f32_16x16x32_bf16(pa0, vb[dt * 2],     oacc[dt], 0, 0, 0);
            oacc[dt] = __builtin_amdgcn_mfma_f32_16x16x32_bf16(pa1, vb[dt * 2 + 1], oacc[dt], 0, 0, 0);
        }
    }

    // per-q softmax denominators, in-register (16-lane groups share q)
    float invq[4];
#pragma unroll
    for (int reg = 0; reg < 4; ++reg) {
        float l = lpart[reg];
#pragma unroll
        for (int m = 8; m >= 1; m >>= 1) l += __shfl_xor(l, m);
        invq[reg] = 1.0f / l;
    }

    // bins -> bf16 into binsBf (aliases Pst; in-wave ordering)
    {
        int q = lane >> 2, r0 = (lane & 3) * 16;
#pragma unroll
        for (int j = 0; j < 4; ++j) {
            float4 f = *(const float4*)&bins[q * 68 + r0 + j * 4];
            short4 o;
            o.x = f2bf(f.x); o.y = f2bf(f.y); o.z = f2bf(f.z); o.w = f2bf(f.w);
            *(short4*)&binsBf[q * 72 + r0 + j * 4] = o;
        }
    }

    // rel_out = bins @ relv, all 4 d-tiles (bf16 transposed table); combine + store
    bf16x8 ba0 = *(const bf16x8*)&binsBf[cl * 72 + quad * 8];
    bf16x8 ba1 = *(const bf16x8*)&binsBf[cl * 72 + 32 + quad * 8];
#pragma unroll
    for (int dt = 0; dt < 4; ++dt) {
        const short* rp = relvT + (size_t)(dt * 16 + cl) * 64 + quad * 8;
        bf16x8 rv0 = *(const bf16x8*)rp;
        bf16x8 rv1 = *(const bf16x8*)(rp + 32);
        f32x4 racc = (f32x4){0.f, 0.f, 0.f, 0.f};
        racc = __builtin_amdgcn_mfma_f32_16x16x32_bf16(ba0, rv0, racc, 0, 0, 0);
        racc = __builtin_amdgcn_mfma_f32_16x16x32_bf16(ba1, rv1, racc, 0, 0, 0);
#pragma unroll
        for (int reg = 0; reg < 4; ++reg) {
            int q = quad * 4 + reg;
            float val = (oacc[dt][reg] + 0.25f * racc[reg]) * invq[reg];
            attn_b[(size_t)(b * 512 + q0 + q) * 1024 + h * 64 + dt * 16 + cl] = f2bf(val);
        }
    }
}

extern "C" void kernel_launch(void* const* d_in, const int* in_sizes, int n_in,
                              void* d_out, int out_size, void* d_ws, size_t ws_size,
                              hipStream_t stream)
{
    const float* q_in = (const float*)d_in[0];
    const float* k_in = (const float*)d_in[1];
    const float* v_in = (const float*)d_in[2];
    const int*   mask = (const int*)d_in[3];
    const float* Wq   = (const float*)d_in[4];
    const float* bq   = (const float*)d_in[5];
    const float* Wk   = (const float*)d_in[6];
    const float* bk   = (const float*)d_in[7];
    const float* Wv   = (const float*)d_in[8];
    const float* bv   = (const float*)d_in[9];
    const float* Wo   = (const float*)d_in[10];
    const float* bo   = (const float*)d_in[11];
    const float* relk = (const float*)d_in[12];
    const float* relv = (const float*)d_in[13];

    char* ws = (char*)d_ws;
    short* qb     = (short*)(ws);                  // 4MB
    short* kb     = (short*)(ws + (4u  << 20));    // 4MB
    short* vt     = (short*)(ws + (8u  << 20));    // 4MB
    short* attn_b = (short*)(ws + (12u << 20));    // 4MB
    short* Xq     = (short*)(ws + (16u << 20));    // 4MB
    short* Xk     = (short*)(ws + (20u << 20));
    short* Xv     = (short*)(ws + (24u << 20));
    short* Wqb    = (short*)(ws + (28u << 20));    // 2MB
    short* Wkb    = (short*)(ws + (30u << 20));
    short* Wvb    = (short*)(ws + (32u << 20));
    short* Wob    = (short*)(ws + (34u << 20));
    short* relkb  = (short*)(ws + (36u << 20));            // 8KB
    short* relvT  = (short*)(ws + (36u << 20) + 8192);     // 8KB

    cast_all<<<10248, 256, 0, stream>>>(q_in, k_in, v_in, Wq, Wk, Wv, Wo, relk, relv,
                                        Xq, Xk, Xv, Wqb, Wkb, Wvb, Wob, relkb, relvT);

    gemm12864<<<dim3(16, 16, 3), 256, 0, stream>>>(
        Xq, Xk, Xv, Wqb, Wkb, Wvb, bq, bk, bv, qb, kb, vt, 1);

    attn_kernel<<<dim3(2048), 64, 0, stream>>>(qb, kb, vt, mask, relkb, relvT, attn_b);

    gemm12864<<<dim3(16, 16, 1), 256, 0, stream>>>(
        attn_b, attn_b, attn_b, Wob, Wob, Wob, bo, bo, bo,
        (void*)d_out, (void*)d_out, (void*)d_out, 0);
}

// Round 3
// 236.430 us; speedup vs baseline: 1.1682x; 1.0400x over previous
//
#include <hip/hip_runtime.h>

// B=4, S=512, HID=1024, H=16, D=64, NREL=64
// ws: qb bf16(B,H,S,D) | kb bf16(B,H,S,D) | vt bf16(B,H,D,S) | attn_b bf16(B*S,HID)
//     Xq,Xk,Xv bf16 | Wqb,Wkb,Wvb,Wob bf16 | relkb bf16(64,64) | relvT bf16(64,64) | masku8 (B,S,S) u8

typedef __attribute__((ext_vector_type(8))) short bf16x8 __attribute__((may_alias));
typedef __attribute__((ext_vector_type(4))) float f32x4;

__device__ __forceinline__ short f2bf(float x) {
    unsigned u = __float_as_uint(x);
    u += 0x7fff + ((u >> 16) & 1);          // RNE; finite inputs
    return (short)(u >> 16);
}

__device__ __forceinline__ void async16(void* lds, const void* g) {
    __builtin_amdgcn_global_load_lds(
        (const __attribute__((address_space(1))) void*)g,
        (__attribute__((address_space(3))) void*)lds, 16, 0, 0);
}

// ---------- fused fp32 -> bf16 cast of 3 X + 4 W + rel tables + mask int32->u8 ----------
__global__ __launch_bounds__(256)
void cast_all(const float* __restrict__ x0, const float* __restrict__ x1, const float* __restrict__ x2,
              const float* __restrict__ w0, const float* __restrict__ w1,
              const float* __restrict__ w2, const float* __restrict__ w3,
              const float* __restrict__ rk, const float* __restrict__ rv,
              const int* __restrict__ mask,
              short* __restrict__ y0, short* __restrict__ y1, short* __restrict__ y2,
              short* __restrict__ u0, short* __restrict__ u1,
              short* __restrict__ u2, short* __restrict__ u3,
              short* __restrict__ rkb, short* __restrict__ rvT,
              unsigned char* __restrict__ mu8)
{
    size_t i = (size_t)blockIdx.x * 256 + threadIdx.x;
    if (i < 2621440u) {
        const float* src; short* dst; size_t off;
        if (i < 3u*524288u) {
            int s = (int)(i / 524288u); off = i % 524288u;
            src = s == 0 ? x0 : (s == 1 ? x1 : x2);
            dst = s == 0 ? y0 : (s == 1 ? y1 : y2);
        } else {
            size_t j = i - 3u*524288u;
            int s = (int)(j / 262144u); off = j % 262144u;
            src = s == 0 ? w0 : (s == 1 ? w1 : (s == 2 ? w2 : w3));
            dst = s == 0 ? u0 : (s == 1 ? u1 : (s == 2 ? u2 : u3));
        }
        float4 f = ((const float4*)src)[off];
        short4 o; o.x = f2bf(f.x); o.y = f2bf(f.y); o.z = f2bf(f.z); o.w = f2bf(f.w);
        ((short4*)dst)[off] = o;
    } else if (i < 2621440u + 1024u) {
        size_t off = i - 2621440u;                 // relk: straight cast, 64x64
        float4 f = ((const float4*)rk)[off];
        short4 o; o.x = f2bf(f.x); o.y = f2bf(f.y); o.z = f2bf(f.z); o.w = f2bf(f.w);
        ((short4*)rkb)[off] = o;
    } else if (i < 2622464u + 1024u) {
        int m = (int)(i - 2622464u);               // relv: transpose to [d][r], 64x64
        int d = m >> 4, r0 = (m & 15) * 4;
        short4 o;
        o.x = f2bf(rv[(size_t)(r0 + 0) * 64 + d]);
        o.y = f2bf(rv[(size_t)(r0 + 1) * 64 + d]);
        o.z = f2bf(rv[(size_t)(r0 + 2) * 64 + d]);
        o.w = f2bf(rv[(size_t)(r0 + 3) * 64 + d]);
        *(short4*)&rvT[d * 64 + r0] = o;
    } else if (i < 2623488u + 262144u) {
        size_t m = i - 2623488u;                   // mask: int32 -> u8 (ids in 0..63)
        int4 v = ((const int4*)mask)[m];
        uchar4 o;
        o.x = (unsigned char)v.x; o.y = (unsigned char)v.y;
        o.z = (unsigned char)v.z; o.w = (unsigned char)v.w;
        ((uchar4*)mu8)[m] = o;
    }
}

// ---------- bf16 MFMA GEMM, tile 128(M)x64(N), BK=64, dbuf: O = A @ B^T + bias ----------
// 4 waves in 2x2; wave does 64(M)x32(N) = 4x2 MFMA tiles.
// mode 0: O fp32 flat (M,1024). mode 1: O bf16; z<2 -> (b,h,s,d); z==2 -> (b,h,d,s).
__global__ __launch_bounds__(256)
void gemm12864(const short* __restrict__ A0, const short* __restrict__ A1, const short* __restrict__ A2,
               const short* __restrict__ B0, const short* __restrict__ B1, const short* __restrict__ B2,
               const float* __restrict__ c0, const float* __restrict__ c1, const float* __restrict__ c2,
               void* __restrict__ O0, void* __restrict__ O1, void* __restrict__ O2,
               int mode)
{
    __shared__ short ldsw[2 * 12288];   // [buf][A 128*64 | B 64*64]; epilogue reuses as Tls

    const int z = blockIdx.z;
    const short* A    = z == 0 ? A0 : (z == 1 ? A1 : A2);
    const short* Bm   = z == 0 ? B0 : (z == 1 ? B1 : B2);
    const float* bias = z == 0 ? c0 : (z == 1 ? c1 : c2);
    void*        O    = z == 0 ? O0 : (z == 1 ? O1 : O2);

    const int t = threadIdx.x;
    const int lane = t & 63, w = t >> 6;
    const int wr = w >> 1, wc = w & 1;            // wave 2x2: wr -> 64-row half, wc -> 32-col half
    const int quad = lane >> 4, cl = lane & 15;
    const int rowBase = blockIdx.y * 128;
    const int colBase = blockIdx.x * 64;
    const int gl = ((lane & 7) - (lane >> 3)) & 7;

    f32x4 acc[4][2];
#pragma unroll
    for (int i = 0; i < 4; ++i)
#pragma unroll
        for (int j = 0; j < 2; ++j) acc[i][j] = (f32x4){0.f, 0.f, 0.f, 0.f};

    const int rstage = w * 8 + (lane >> 3);
    const short* Ag = A  + (size_t)(rowBase + rstage) * 1024 + gl * 8;
    const short* Bg = Bm + (size_t)(colBase + rstage) * 1024 + gl * 8;

    // prologue: stage tile 0 into buf 0
    {
        short* Als = ldsw;
        short* Bls = ldsw + 8192;
#pragma unroll
        for (int i = 0; i < 4; ++i)
            async16(&Als[(i * 32 + w * 8) * 64], Ag + (size_t)i * 32 * 1024);
#pragma unroll
        for (int i = 0; i < 2; ++i)
            async16(&Bls[(i * 32 + w * 8) * 64], Bg + (size_t)i * 32 * 1024);
    }

    for (int it = 0; it < 16; ++it) {
        const int cur = it & 1;
        __syncthreads();                          // drains vmcnt -> buf[cur] valid
        if (it < 15) {
            short* Als = ldsw + (cur ^ 1) * 12288;
            short* Bls = Als + 8192;
            const int k0 = (it + 1) * 64;
#pragma unroll
            for (int i = 0; i < 4; ++i)
                async16(&Als[(i * 32 + w * 8) * 64], Ag + (size_t)i * 32 * 1024 + k0);
#pragma unroll
            for (int i = 0; i < 2; ++i)
                async16(&Bls[(i * 32 + w * 8) * 64], Bg + (size_t)i * 32 * 1024 + k0);
        }
        const short* Als = ldsw + cur * 12288;
        const short* Bls = Als + 8192;
#pragma unroll
        for (int kk = 0; kk < 2; ++kk) {
            bf16x8 a[4], b[2];
#pragma unroll
            for (int mi = 0; mi < 4; ++mi) {
                int r = wr * 64 + mi * 16 + cl;
                int s = (kk * 4 + quad + r) & 7;
                a[mi] = *(const bf16x8*)&Als[r * 64 + s * 8];
            }
#pragma unroll
            for (int ni = 0; ni < 2; ++ni) {
                int r = wc * 32 + ni * 16 + cl;
                int s = (kk * 4 + quad + r) & 7;
                b[ni] = *(const bf16x8*)&Bls[r * 64 + s * 8];
            }
#pragma unroll
            for (int mi = 0; mi < 4; ++mi)
#pragma unroll
                for (int ni = 0; ni < 2; ++ni)
                    acc[mi][ni] = __builtin_amdgcn_mfma_f32_16x16x32_bf16(
                        a[mi], b[ni], acc[mi][ni], 0, 0, 0);
        }
    }

    if (mode == 0) {
        // flat f32 (M,1024)
#pragma unroll
        for (int mi = 0; mi < 4; ++mi)
#pragma unroll
            for (int ni = 0; ni < 2; ++ni) {
                int col = colBase + wc * 32 + ni * 16 + cl;
                float bv = bias[col];
#pragma unroll
                for (int reg = 0; reg < 4; ++reg) {
                    int row = rowBase + wr * 64 + mi * 16 + quad * 4 + reg;
                    ((float*)O)[(size_t)row * 1024 + col] = acc[mi][ni][reg] + bv;
                }
            }
        return;
    }

    __syncthreads();                              // staging reads done before Tls reuse
    short* Tls = ldsw;
    if (z == 2) {
        // vt (b,h,d,s): Tls[64][136]
#pragma unroll
        for (int mi = 0; mi < 4; ++mi)
#pragma unroll
            for (int ni = 0; ni < 2; ++ni) {
                int d = wc * 32 + ni * 16 + cl;
                float bv = bias[colBase + d];
                short4 pk;
                pk.x = f2bf(acc[mi][ni][0] + bv);
                pk.y = f2bf(acc[mi][ni][1] + bv);
                pk.z = f2bf(acc[mi][ni][2] + bv);
                pk.w = f2bf(acc[mi][ni][3] + bv);
                int sl = wr * 64 + mi * 16 + quad * 4;
                *(short4*)&Tls[d * 136 + sl] = pk;
            }
        __syncthreads();
        int d = t >> 2, s0 = (t & 3) * 32;
        int bb = rowBase >> 9, sBase = rowBase & 511, hh = colBase >> 6;
        short* dst = (short*)O + (((size_t)(bb * 16 + hh) * 64 + d) << 9) + sBase + s0;
#pragma unroll
        for (int j = 0; j < 4; ++j)
            *(bf16x8*)(dst + j * 8) = *(const bf16x8*)&Tls[d * 136 + s0 + j * 8];
    } else {
        // bhsd: Tls[128][72] (one head: colBase is 64-aligned, N=64)
#pragma unroll
        for (int mi = 0; mi < 4; ++mi)
#pragma unroll
            for (int ni = 0; ni < 2; ++ni) {
                int d = wc * 32 + ni * 16 + cl;
                float bv = bias[colBase + d];
#pragma unroll
                for (int reg = 0; reg < 4; ++reg) {
                    int sl = wr * 64 + mi * 16 + quad * 4 + reg;
                    Tls[sl * 72 + d] = f2bf(acc[mi][ni][reg] + bv);
                }
            }
        __syncthreads();
        int sl = t >> 1, half = t & 1;
        int bb = rowBase >> 9, sBase = rowBase & 511, hh = colBase >> 6;
        short* dst = (short*)O + (((size_t)(bb * 16 + hh) * 512 + sBase + sl) << 6) + half * 32;
#pragma unroll
        for (int j = 0; j < 4; ++j)
            *(bf16x8*)(dst + j * 8) = *(const bf16x8*)&Tls[sl * 72 + half * 32 + j * 8];
    }
}

// ---------------- Attention: 512 blocks x 4 independent waves ----------------
// Wave w of block bid runs the proven 1-wave program for q-tile q0 = (bid>>6)*64 + w*16,
// on its own LDS slice. Zero barriers, zero cross-wave sharing. 4x fewer blocks than R0.
// Mask read as u8 (1MB total -> fits per-XCD L2 alongside K/V; no L2 thrash).
// Grid swizzle: bh = bid & 63 so same-bh blocks share an XCD.
#define AT_BINS 4352
#define AT_PST  8704
#define AT_SLICE 11264

__global__ __launch_bounds__(256)
void attn_kernel(const short* __restrict__ qg, const short* __restrict__ kg,
                 const short* __restrict__ vtg, const unsigned char* __restrict__ mu8,
                 const short* __restrict__ relkb, const short* __restrict__ relvT,
                 short* __restrict__ attn_b)
{
    __shared__ __align__(16) char pool[4 * AT_SLICE];
    const int t = threadIdx.x;
    const int lane = t & 63, w = t >> 6;
    char* mypool = pool + w * AT_SLICE;
    float* qwr    = (float*)mypool;
    float* bins   = (float*)(mypool + AT_BINS);
    short* Pst    = (short*)(mypool + AT_PST);
    short* binsBf = Pst;                       // aliases Pst after K-loop (Pst dead)

    const int quad = lane >> 4, cl = lane & 15;
    const int bid = blockIdx.x;
    const int bh = bid & 63, qq = bid >> 6;    // XCD-friendly: bh%8 fixes XCD
    const int b = bh >> 4, h = bh & 15, q0 = qq * 64 + w * 16;

    const short* qbase = qg  + ((size_t)bh * 512 + q0) * 64;
    const short* kbase = kg  + (size_t)bh * 512 * 64;
    const short* vbase = vtg + (size_t)bh * 64 * 512;
    const unsigned char* mb = mu8 + (size_t)b * 512 * 512 + (size_t)q0 * 512;

    // zero bins (wave-private slice)
    for (int i = lane; i < 16 * 68; i += 64) bins[i] = 0.f;

    // Q A-fragments direct from global
    bf16x8 qa0 = *(const bf16x8*)(qbase + cl * 64 + quad * 8);
    bf16x8 qa1 = *(const bf16x8*)(qbase + cl * 64 + 32 + quad * 8);

    // qrel: all 4 r-tiles (bf16 table, vector loads)
#pragma unroll
    for (int rt = 0; rt < 4; ++rt) {
        const short* kp = relkb + (size_t)(rt * 16 + cl) * 64 + quad * 8;
        bf16x8 rb0 = *(const bf16x8*)kp;
        bf16x8 rb1 = *(const bf16x8*)(kp + 32);
        f32x4 qr = (f32x4){0.f, 0.f, 0.f, 0.f};
        qr = __builtin_amdgcn_mfma_f32_16x16x32_bf16(qa0, rb0, qr, 0, 0, 0);
        qr = __builtin_amdgcn_mfma_f32_16x16x32_bf16(qa1, rb1, qr, 0, 0, 0);
#pragma unroll
        for (int reg = 0; reg < 4; ++reg)
            qwr[(quad * 4 + reg) * 68 + rt * 16 + cl] = qr[reg];
    }

    // ---- K-loop: 8 chunks of 64 keys ----
    f32x4 oacc[4];
#pragma unroll
    for (int dt = 0; dt < 4; ++dt) oacc[dt] = (f32x4){0.f, 0.f, 0.f, 0.f};
    float lpart[4] = {0.f, 0.f, 0.f, 0.f};

    for (int c = 0; c < 8; ++c) {
        const int k0 = c * 64;
        // mask ids for this chunk (u8 loads, issue before compute)
        int ids[4][4];
#pragma unroll
        for (int nt = 0; nt < 4; ++nt)
#pragma unroll
            for (int reg = 0; reg < 4; ++reg)
                ids[nt][reg] = mb[(size_t)(quad * 4 + reg) * 512 + k0 + nt * 16 + cl];

        // V prefetch for this chunk (used after softmax)
        bf16x8 vb[8];
#pragma unroll
        for (int dt = 0; dt < 4; ++dt) {
            const short* vp = vbase + (size_t)(dt * 16 + cl) * 512 + k0 + quad * 8;
            vb[dt * 2]     = *(const bf16x8*)vp;
            vb[dt * 2 + 1] = *(const bf16x8*)(vp + 32);
        }

        // QK^T + softmax numerator -> Pst
#pragma unroll
        for (int nt = 0; nt < 4; ++nt) {
            const int kidx = k0 + nt * 16 + cl;
            const short* kp = kbase + (size_t)kidx * 64 + quad * 8;
            bf16x8 kb0 = *(const bf16x8*)kp;
            bf16x8 kb1 = *(const bf16x8*)(kp + 32);
            f32x4 s = (f32x4){0.f, 0.f, 0.f, 0.f};
            __builtin_amdgcn_s_setprio(1);
            s = __builtin_amdgcn_mfma_f32_16x16x32_bf16(qa0, kb0, s, 0, 0, 0);
            s = __builtin_amdgcn_mfma_f32_16x16x32_bf16(qa1, kb1, s, 0, 0, 0);
            __builtin_amdgcn_s_setprio(0);
#pragma unroll
            for (int reg = 0; reg < 4; ++reg) {
                int q = quad * 4 + reg;
                int id = ids[nt][reg];
                float sc = (s[reg] + 0.25f * qwr[q * 68 + id]) * 0.125f;
                float p = (id == 0) ? 0.f : __expf(sc);   // no-max softmax; masked -> 0
                lpart[reg] += p;
                atomicAdd(&bins[q * 68 + id], p);
                Pst[q * 72 + nt * 16 + cl] = f2bf(p);
            }
        }
        // P C-layout -> A-layout via wave-private LDS (in-wave RAW via lgkmcnt)
        bf16x8 pa0 = *(const bf16x8*)&Pst[cl * 72 + quad * 8];
        bf16x8 pa1 = *(const bf16x8*)&Pst[cl * 72 + 32 + quad * 8];
        __builtin_amdgcn_s_setprio(1);
#pragma unroll
        for (int dt = 0; dt < 4; ++dt) {
            oacc[dt] = __builtin_amdgcn_mfma_f32_16x16x32_bf16(pa0, vb[dt * 2],     oacc[dt], 0, 0, 0);
            oacc[dt] = __builtin_amdgcn_mfma_f32_16x16x32_bf16(pa1, vb[dt * 2 + 1], oacc[dt], 0, 0, 0);
        }
        __builtin_amdgcn_s_setprio(0);
    }

    // per-q softmax denominators, in-register (16-lane groups share q)
    float invq[4];
#pragma unroll
    for (int reg = 0; reg < 4; ++reg) {
        float l = lpart[reg];
#pragma unroll
        for (int m = 8; m >= 1; m >>= 1) l += __shfl_xor(l, m);
        invq[reg] = 1.0f / l;
    }

    // bins -> bf16 into binsBf (aliases Pst; in-wave ordering)
    {
        int q = lane >> 2, r0 = (lane & 3) * 16;
#pragma unroll
        for (int j = 0; j < 4; ++j) {
            float4 f = *(const float4*)&bins[q * 68 + r0 + j * 4];
            short4 o;
            o.x = f2bf(f.x); o.y = f2bf(f.y); o.z = f2bf(f.z); o.w = f2bf(f.w);
            *(short4*)&binsBf[q * 72 + r0 + j * 4] = o;
        }
    }

    // rel_out = bins @ relv, all 4 d-tiles (bf16 transposed table); combine + store
    bf16x8 ba0 = *(const bf16x8*)&binsBf[cl * 72 + quad * 8];
    bf16x8 ba1 = *(const bf16x8*)&binsBf[cl * 72 + 32 + quad * 8];
#pragma unroll
    for (int dt = 0; dt < 4; ++dt) {
        const short* rp = relvT + (size_t)(dt * 16 + cl) * 64 + quad * 8;
        bf16x8 rv0 = *(const bf16x8*)rp;
        bf16x8 rv1 = *(const bf16x8*)(rp + 32);
        f32x4 racc = (f32x4){0.f, 0.f, 0.f, 0.f};
        racc = __builtin_amdgcn_mfma_f32_16x16x32_bf16(ba0, rv0, racc, 0, 0, 0);
        racc = __builtin_amdgcn_mfma_f32_16x16x32_bf16(ba1, rv1, racc, 0, 0, 0);
#pragma unroll
        for (int reg = 0; reg < 4; ++reg) {
            int q = quad * 4 + reg;
            float val = (oacc[dt][reg] + 0.25f * racc[reg]) * invq[reg];
            attn_b[(size_t)(b * 512 + q0 + q) * 1024 + h * 64 + dt * 16 + cl] = f2bf(val);
        }
    }
}

extern "C" void kernel_launch(void* const* d_in, const int* in_sizes, int n_in,
                              void* d_out, int out_size, void* d_ws, size_t ws_size,
                              hipStream_t stream)
{
    const float* q_in = (const float*)d_in[0];
    const float* k_in = (const float*)d_in[1];
    const float* v_in = (const float*)d_in[2];
    const int*   mask = (const int*)d_in[3];
    const float* Wq   = (const float*)d_in[4];
    const float* bq   = (const float*)d_in[5];
    const float* Wk   = (const float*)d_in[6];
    const float* bk   = (const float*)d_in[7];
    const float* Wv   = (const float*)d_in[8];
    const float* bv   = (const float*)d_in[9];
    const float* Wo   = (const float*)d_in[10];
    const float* bo   = (const float*)d_in[11];
    const float* relk = (const float*)d_in[12];
    const float* relv = (const float*)d_in[13];

    char* ws = (char*)d_ws;
    short* qb     = (short*)(ws);                  // 4MB
    short* kb     = (short*)(ws + (4u  << 20));    // 4MB
    short* vt     = (short*)(ws + (8u  << 20));    // 4MB
    short* attn_b = (short*)(ws + (12u << 20));    // 4MB
    short* Xq     = (short*)(ws + (16u << 20));    // 4MB
    short* Xk     = (short*)(ws + (20u << 20));
    short* Xv     = (short*)(ws + (24u << 20));
    short* Wqb    = (short*)(ws + (28u << 20));    // 2MB
    short* Wkb    = (short*)(ws + (30u << 20));
    short* Wvb    = (short*)(ws + (32u << 20));
    short* Wob    = (short*)(ws + (34u << 20));
    short* relkb  = (short*)(ws + (36u << 20));                    // 8KB
    short* relvT  = (short*)(ws + (36u << 20) + 8192);             // 8KB
    unsigned char* masku8 = (unsigned char*)(ws + (36u << 20) + 16384); // 1MB

    cast_all<<<11272, 256, 0, stream>>>(q_in, k_in, v_in, Wq, Wk, Wv, Wo, relk, relv, mask,
                                        Xq, Xk, Xv, Wqb, Wkb, Wvb, Wob, relkb, relvT, masku8);

    gemm12864<<<dim3(16, 16, 3), 256, 0, stream>>>(
        Xq, Xk, Xv, Wqb, Wkb, Wvb, bq, bk, bv, qb, kb, vt, 1);

    attn_kernel<<<dim3(512), 256, 0, stream>>>(qb, kb, vt, masku8, relkb, relvT, attn_b);

    gemm12864<<<dim3(16, 16, 1), 256, 0, stream>>>(
        attn_b, attn_b, attn_b, Wob, Wob, Wob, bo, bo, bo,
        (void*)d_out, (void*)d_out, (void*)d_out, 0);
}